// Round 6
// baseline (2081.088 us; speedup 1.0000x reference)
//
#include <hip/hip_runtime.h>
#include <hip/hip_bf16.h>

#define BB 128
#define LL 200
#define DD 512
#define HH 8
#define DK 64
#define NBLK 2
#define BL (BB*LL)

typedef unsigned short ushort_t;
typedef unsigned int uint_t;
typedef __attribute__((ext_vector_type(8))) short short8;
typedef __attribute__((ext_vector_type(4))) float f32x4;

__device__ inline ushort_t f2b(float x) {
    unsigned u = __float_as_uint(x);
    unsigned r = (u + 0x7FFF + ((u >> 16) & 1)) >> 16;
    return (ushort_t)r;
}

__device__ inline void gload16(const void* g, void* l) {
    __builtin_amdgcn_global_load_lds((const __attribute__((address_space(1))) void*)g,
                                     (__attribute__((address_space(3))) void*)l,
                                     16, 0, 0);
}

// ---------------- masks ----------------
__global__ __launch_bounds__(256) void mask_kernel(const int* __restrict__ logs,
                                                   const int* __restrict__ entire,
                                                   float* __restrict__ tlf,
                                                   float* __restrict__ keepf,
                                                   float* __restrict__ kmf) {
    int i = blockIdx.x * 256 + threadIdx.x;
    if (i < BL) {
        float t = (logs[i] == 0) ? 1.f : 0.f;
        tlf[i] = t;
        keepf[i] = 1.f - t;
        kmf[i] = (logs[i] == 0 && entire[i] != 0) ? 1.f : 0.f;
    }
}

// target = seqs_embs * keep
__global__ __launch_bounds__(256) void init_target(const float* __restrict__ emb,
                                                   const float* __restrict__ keepf,
                                                   float* __restrict__ tgt) {
    int row = blockIdx.x;
    int t = threadIdx.x;
    float kf = keepf[row];
    size_t base = (size_t)row * DD;
    tgt[base + t] = emb[base + t] * kf;
    tgt[base + t + 256] = emb[base + t + 256] * kf;
}

// src_bf16 = emb * tl
__global__ __launch_bounds__(256) void src_kernel(const float* __restrict__ emb,
                                                  const float* __restrict__ tlf,
                                                  ushort_t* __restrict__ srcb) {
    int row = blockIdx.x;
    int t = threadIdx.x;
    float s = tlf[row];
    size_t base = (size_t)row * DD;
    srcb[base + t] = f2b(emb[base + t] * s);
    srcb[base + t + 256] = f2b(emb[base + t + 256] * s);
}

// weight transpose + bf16: Wt[n][k] = W[k][n]; dst = Wt + z*zstride + base
__global__ __launch_bounds__(256) void wtrans_kernel(const float* __restrict__ W,
                                                     ushort_t* __restrict__ Wt,
                                                     size_t zstride, size_t base) {
    __shared__ float ts[32][33];
    int tx = threadIdx.x & 31, ty = threadIdx.x >> 5;
    int bx = blockIdx.x * 32, by = blockIdx.y * 32;
    const float* Wm = W + (size_t)blockIdx.z * DD * DD;
    ushort_t* Wtm = Wt + (size_t)blockIdx.z * zstride + base;
    #pragma unroll
    for (int i = 0; i < 4; i++) {
        int r = ty + i * 8;
        ts[r][tx] = Wm[(size_t)(by + r) * DD + bx + tx];
    }
    __syncthreads();
    #pragma unroll
    for (int i = 0; i < 4; i++) {
        int r = ty + i * 8;
        Wtm[(size_t)(bx + r) * DD + by + tx] = f2b(ts[tx][r]);
    }
}

// ---------------- layernorm ----------------
__global__ __launch_bounds__(256) void ln_kernel(const float* __restrict__ x,
                                                 const float* __restrict__ addx,
                                                 float* __restrict__ outf,
                                                 ushort_t* __restrict__ outb,
                                                 const float* __restrict__ g,
                                                 const float* __restrict__ bt,
                                                 const float* __restrict__ keepf) {
    int row = blockIdx.x;
    int t = threadIdx.x;
    size_t base = (size_t)row * DD;
    float v0 = x[base + t], v1 = x[base + t + 256];
    if (addx) { v0 += addx[base + t]; v1 += addx[base + t + 256]; }
    float s = v0 + v1, sq = v0 * v0 + v1 * v1;
    #pragma unroll
    for (int off = 32; off; off >>= 1) {
        s += __shfl_xor(s, off);
        sq += __shfl_xor(sq, off);
    }
    __shared__ float rs[4], rq[4];
    int wid = t >> 6, lane = t & 63;
    if (lane == 0) { rs[wid] = s; rq[wid] = sq; }
    __syncthreads();
    s = rs[0] + rs[1] + rs[2] + rs[3];
    sq = rq[0] + rq[1] + rq[2] + rq[3];
    float mean = s * (1.f / DD);
    float var = sq * (1.f / DD) - mean * mean;
    float rstd = rsqrtf(fmaxf(var, 0.f) + 1e-8f);
    float kf = keepf ? keepf[row] : 1.f;
    float o0 = ((v0 - mean) * rstd * g[t] + bt[t]) * kf;
    float o1 = ((v1 - mean) * rstd * g[t + 256] + bt[t + 256]) * kf;
    if (outf) { outf[base + t] = o0; outf[base + t + 256] = o1; }
    if (outb) { outb[base + t] = f2b(o0); outb[base + t + 256] = f2b(o1); }
}

// ---------------- bf16 MFMA GEMM: C = A @ Wt^T + bias ----------------
// mode 1: Cb = bf16(relu(acc+bias)) ; mode 2: Cf = (Cf+acc+bias)*keepf
__global__ __launch_bounds__(256) void gemm_mfma(const ushort_t* __restrict__ A,
                                                 const ushort_t* __restrict__ Bt,
                                                 const float* __restrict__ bias,
                                                 float* __restrict__ Cf,
                                                 ushort_t* __restrict__ Cb,
                                                 const float* __restrict__ keepf,
                                                 int mode, int M, int N, int K) {
    __shared__ ushort_t sA[128 * 32];
    __shared__ ushort_t sB[128 * 32];
    int t = threadIdx.x;
    int w = t >> 6, lane = t & 63;
    int wm = w & 1, wn = w >> 1;
    int m0 = blockIdx.x * 128, n0 = blockIdx.y * 128;
    int lr = lane & 15, lq = lane >> 4;

    f32x4 acc[4][4] = {};

    for (int k0 = 0; k0 < K; k0 += 32) {
        #pragma unroll
        for (int r = 0; r < 2; r++) {
            int e = (r * 256 + t) * 8;
            int row = e >> 5, col = e & 31;
            gload16(A + (size_t)(m0 + row) * K + k0 + col, sA + (r * 256 + w * 64) * 8);
            gload16(Bt + (size_t)(n0 + row) * K + k0 + col, sB + (r * 256 + w * 64) * 8);
        }
        __syncthreads();

        short8 af[4], bf[4];
        #pragma unroll
        for (int mt = 0; mt < 4; mt++)
            af[mt] = *(const short8*)(sA + (wm * 64 + mt * 16 + lr) * 32 + lq * 8);
        #pragma unroll
        for (int nt = 0; nt < 4; nt++)
            bf[nt] = *(const short8*)(sB + (wn * 64 + nt * 16 + lr) * 32 + lq * 8);
        #pragma unroll
        for (int mt = 0; mt < 4; mt++)
            #pragma unroll
            for (int nt = 0; nt < 4; nt++)
                acc[mt][nt] = __builtin_amdgcn_mfma_f32_16x16x32_bf16(af[mt], bf[nt], acc[mt][nt], 0, 0, 0);
        __syncthreads();
    }

    #pragma unroll
    for (int nt = 0; nt < 4; nt++) {
        int col = n0 + wn * 64 + nt * 16 + lr;
        float bv = bias[col];
        #pragma unroll
        for (int mt = 0; mt < 4; mt++) {
            int rowb = m0 + wm * 64 + mt * 16 + lq * 4;
            #pragma unroll
            for (int r = 0; r < 4; r++) {
                int row = rowb + r;
                float o = acc[mt][nt][r] + bv;
                size_t idx = (size_t)row * N + col;
                if (mode == 1) {
                    Cb[idx] = f2b(fmaxf(o, 0.f));
                } else {
                    float kf = keepf[row];
                    Cf[idx] = (Cf[idx] + o) * kf;
                }
            }
        }
    }
}

// ---------------- fused Q/K/V projection: grid (200, 4, 3) ----------------
// z=0: qb = lnb@Wq+bq ; z=1: kb = srcb@Wk+bk ; z=2: vb = srcb@Wv+bv (all bf16 out)
__global__ __launch_bounds__(256) void gemm_qkv(const ushort_t* __restrict__ Aq,
                                                const ushort_t* __restrict__ Akv,
                                                const ushort_t* __restrict__ Bqkv,
                                                const float* __restrict__ bq,
                                                const float* __restrict__ bk,
                                                const float* __restrict__ bv,
                                                ushort_t* __restrict__ qkv) {
    __shared__ ushort_t sA[128 * 32];
    __shared__ ushort_t sB[128 * 32];
    int z = blockIdx.z;
    const ushort_t* A = (z == 0) ? Aq : Akv;
    const ushort_t* Bt = Bqkv + (size_t)z * DD * DD;
    const float* bias = (z == 0) ? bq : (z == 1) ? bk : bv;
    ushort_t* C = qkv + (size_t)z * BL * DD;

    int t = threadIdx.x;
    int w = t >> 6, lane = t & 63;
    int wm = w & 1, wn = w >> 1;
    int m0 = blockIdx.x * 128, n0 = blockIdx.y * 128;
    int lr = lane & 15, lq = lane >> 4;

    f32x4 acc[4][4] = {};

    for (int k0 = 0; k0 < DD; k0 += 32) {
        #pragma unroll
        for (int r = 0; r < 2; r++) {
            int e = (r * 256 + t) * 8;
            int row = e >> 5, col = e & 31;
            gload16(A + (size_t)(m0 + row) * DD + k0 + col, sA + (r * 256 + w * 64) * 8);
            gload16(Bt + (size_t)(n0 + row) * DD + k0 + col, sB + (r * 256 + w * 64) * 8);
        }
        __syncthreads();

        short8 af[4], bf[4];
        #pragma unroll
        for (int mt = 0; mt < 4; mt++)
            af[mt] = *(const short8*)(sA + (wm * 64 + mt * 16 + lr) * 32 + lq * 8);
        #pragma unroll
        for (int nt = 0; nt < 4; nt++)
            bf[nt] = *(const short8*)(sB + (wn * 64 + nt * 16 + lr) * 32 + lq * 8);
        #pragma unroll
        for (int mt = 0; mt < 4; mt++)
            #pragma unroll
            for (int nt = 0; nt < 4; nt++)
                acc[mt][nt] = __builtin_amdgcn_mfma_f32_16x16x32_bf16(af[mt], bf[nt], acc[mt][nt], 0, 0, 0);
        __syncthreads();
    }

    #pragma unroll
    for (int nt = 0; nt < 4; nt++) {
        int col = n0 + wn * 64 + nt * 16 + lr;
        float bv2 = bias[col];
        #pragma unroll
        for (int mt = 0; mt < 4; mt++) {
            int rowb = m0 + wm * 64 + mt * 16 + lq * 4;
            #pragma unroll
            for (int r = 0; r < 4; r++) {
                int row = rowb + r;
                C[(size_t)row * DD + col] = f2b(acc[mt][nt][r] + bv2);
            }
        }
    }
}

// ---------------- attention v4: MFMA, wg per (b,h), 62.7 KB LDS, 2 blocks/CU ----
// LDS: sKP (K[208][72] 29,952 B, later P[64][232] 29,696 B) | sVt[64][232] 29,696 B
//      | floats: kms[256], redm[256], reds[256]  => 62,720 B total
#define ATTN_LDS_BYTES 62720
__global__ __launch_bounds__(256, 2) void attn4_kernel(const ushort_t* __restrict__ q,
                                                       const ushort_t* __restrict__ k,
                                                       const ushort_t* __restrict__ v,
                                                       const float* __restrict__ kmf,
                                                       float* __restrict__ xout) {
    extern __shared__ ushort_t su[];
    ushort_t* sKP = su;                 // K: [208][72] / P: [64][232]
    ushort_t* sVt = su + 14976;         // [64][232]
    float* fl = (float*)(su + 29824);
    float* kms = fl;                    // [256]
    float* redm = fl + 256;             // [256]
    float* reds = fl + 512;             // [256]

    int t = threadIdx.x;
    int b = blockIdx.x >> 3, h = blockIdx.x & 7;
    int w = t >> 6, lane = t & 63;
    int lr = lane & 15, lq = lane >> 4;

    const ushort_t* kg = k + (size_t)b * LL * DD + h * DK;
    const ushort_t* vg = v + (size_t)b * LL * DD + h * DK;
    const ushort_t* qg = q + (size_t)b * LL * DD + h * DK;
    float* og = xout + (size_t)b * LL * DD + h * DK;

    // stage V^T once: word (d*116 + tt) holds keys {2tt, 2tt+1} for dim d
    for (int idx = t; idx < 1024; idx += 256) {
        int s = idx >> 7, tt = idx & 127;
        if (tt < 116) {
            uint_t outw[8];
            if (tt < 100) {
                int j0 = tt * 2;
                uint4 a = *(const uint4*)(vg + (size_t)j0 * DD + s * 8);
                uint4 c = *(const uint4*)(vg + (size_t)(j0 + 1) * DD + s * 8);
                uint_t av[4] = {a.x, a.y, a.z, a.w};
                uint_t cv[4] = {c.x, c.y, c.z, c.w};
                #pragma unroll
                for (int i = 0; i < 8; i++) {
                    uint_t lo = (av[i >> 1] >> ((i & 1) * 16)) & 0xFFFFu;
                    uint_t hi = (cv[i >> 1] >> ((i & 1) * 16)) & 0xFFFFu;
                    outw[i] = lo | (hi << 16);
                }
            } else {
                #pragma unroll
                for (int i = 0; i < 8; i++) outw[i] = 0;
            }
            #pragma unroll
            for (int i = 0; i < 8; i++)
                ((uint_t*)sVt)[(s * 8 + i) * 116 + tt] = outw[i];
        }
    }
    kms[t] = (t < LL) ? kmf[b * LL + t] : 0.f;
    // no barrier needed yet: first use of sVt/kms is after the qtile-0 barrier

    int ntmax = (w == 3) ? 1 : 4;   // keys >= 208 don't exist

    for (int qt = 0; qt < 4; qt++) {
        int q0 = qt * 64;

        // re-stage K [200][64] -> sKP pitch 72 (P overwrote it last qtile), zero 200..207
        for (int idx = t; idx < 1600; idx += 256) {
            int row = idx >> 3, seg = idx & 7;
            *(uint4*)(sKP + row * 72 + seg * 8) = *(const uint4*)(kg + (size_t)row * DD + seg * 8);
        }
        if (t < 64) {
            int row = 200 + (t >> 3), seg = t & 7;
            uint4 z4 = {0, 0, 0, 0};
            *(uint4*)(sKP + row * 72 + seg * 8) = z4;
        }
        // Q fragments direct from global (A-layout = natural row chunks)
        short8 af[2][4];
        #pragma unroll
        for (int ks = 0; ks < 2; ks++)
            #pragma unroll
            for (int mt = 0; mt < 4; mt++) {
                int grow = q0 + mt * 16 + lr;
                if (grow > LL - 1) grow = LL - 1;
                af[ks][mt] = *(const short8*)(qg + (size_t)grow * DD + ks * 32 + lq * 8);
            }
        __syncthreads();

        // S = Q @ K^T ; wave w covers keys w*64..w*64+63
        f32x4 accS[4][4] = {};
        #pragma unroll
        for (int ks = 0; ks < 2; ks++) {
            short8 bf[4];
            for (int nt = 0; nt < ntmax; nt++)
                bf[nt] = *(const short8*)(sKP + (w * 64 + nt * 16 + lr) * 72 + ks * 32 + lq * 8);
            for (int nt = 0; nt < ntmax; nt++)
                #pragma unroll
                for (int mt = 0; mt < 4; mt++)
                    accS[mt][nt] = __builtin_amdgcn_mfma_f32_16x16x32_bf16(af[ks][mt], bf[nt], accS[mt][nt], 0, 0, 0);
        }

        // mask + scale + per-wave row max
        float km[4];
        #pragma unroll
        for (int nt = 0; nt < 4; nt++) km[nt] = kms[w * 64 + nt * 16 + lr];
        float rmax[4][4];
        #pragma unroll
        for (int mt = 0; mt < 4; mt++) {
            #pragma unroll
            for (int r = 0; r < 4; r++) {
                int qrow = q0 + mt * 16 + lq * 4 + r;
                float m = -1e9f;
                #pragma unroll
                for (int nt = 0; nt < 4; nt++) {
                    int j = w * 64 + nt * 16 + lr;
                    bool ok = (j <= qrow) && (km[nt] != 0.f);
                    float s = ok ? accS[mt][nt][r] * 0.125f : -1e9f;
                    accS[mt][nt][r] = s;
                    m = fmaxf(m, s);
                }
                #pragma unroll
                for (int off = 1; off < 16; off <<= 1)
                    m = fmaxf(m, __shfl_xor(m, off));
                rmax[mt][r] = m;
            }
        }
        if (lr == 0) {
            #pragma unroll
            for (int mt = 0; mt < 4; mt++)
                #pragma unroll
                for (int r = 0; r < 4; r++)
                    redm[w * 64 + mt * 16 + lq * 4 + r] = rmax[mt][r];
        }
        __syncthreads();

        // exp + per-wave row sum
        float gmx[4][4], rsum[4][4];
        #pragma unroll
        for (int mt = 0; mt < 4; mt++) {
            #pragma unroll
            for (int r = 0; r < 4; r++) {
                int row = mt * 16 + lq * 4 + r;
                float gm = fmaxf(fmaxf(redm[row], redm[64 + row]),
                                 fmaxf(redm[128 + row], redm[192 + row]));
                gmx[mt][r] = gm;
                float ps = 0.f;
                #pragma unroll
                for (int nt = 0; nt < 4; nt++) {
                    float e = __expf(accS[mt][nt][r] - gm);
                    accS[mt][nt][r] = e;
                    ps += e;
                }
                #pragma unroll
                for (int off = 1; off < 16; off <<= 1)
                    ps += __shfl_xor(ps, off);
                rsum[mt][r] = ps;
            }
        }
        if (lr == 0) {
            #pragma unroll
            for (int mt = 0; mt < 4; mt++)
                #pragma unroll
                for (int r = 0; r < 4; r++)
                    reds[w * 64 + mt * 16 + lq * 4 + r] = rsum[mt][r];
        }
        __syncthreads();

        // normalize -> bf16 P over the K region (K frag reads all completed pre-barrier)
        #pragma unroll
        for (int mt = 0; mt < 4; mt++) {
            #pragma unroll
            for (int r = 0; r < 4; r++) {
                int row = mt * 16 + lq * 4 + r;
                float tot = reds[row] + reds[64 + row] + reds[128 + row] + reds[192 + row];
                float inv = (gmx[mt][r] < -5e8f) ? 0.f : 1.f / tot;
                #pragma unroll
                for (int nt = 0; nt < 4; nt++) {
                    int col = w * 64 + nt * 16 + lr;
                    if (col < 224)
                        sKP[row * 232 + col] = f2b(accS[mt][nt][r] * inv);
                }
            }
        }
        __syncthreads();

        // O = P @ V ; wave w covers d-tile w*16..w*16+15 ; keys 0..223 (224+ not stored)
        f32x4 accO[4] = {};
        #pragma unroll
        for (int ks2 = 0; ks2 < 7; ks2++) {
            short8 bfv = *(const short8*)(sVt + (w * 16 + lr) * 232 + ks2 * 32 + lq * 8);
            #pragma unroll
            for (int mt = 0; mt < 4; mt++) {
                short8 afp = *(const short8*)(sKP + (mt * 16 + lr) * 232 + ks2 * 32 + lq * 8);
                accO[mt] = __builtin_amdgcn_mfma_f32_16x16x32_bf16(afp, bfv, accO[mt], 0, 0, 0);
            }
        }
        #pragma unroll
        for (int mt = 0; mt < 4; mt++) {
            #pragma unroll
            for (int r = 0; r < 4; r++) {
                int row = q0 + mt * 16 + lq * 4 + r;
                if (row < LL)
                    og[(size_t)row * DD + w * 16 + lr] = accO[mt][r];
            }
        }
        __syncthreads();   // P reads done before next qtile re-stages K
    }
}

extern "C" void kernel_launch(void* const* d_in, const int* in_sizes, int n_in,
                              void* d_out, int out_size, void* d_ws, size_t ws_size,
                              hipStream_t stream) {
    const int* log_seqs = (const int*)d_in[0];
    const float* seqs_embs = (const float*)d_in[1];
    const int* entire = (const int*)d_in[2];
    const float* Wq = (const float*)d_in[3];
    const float* bq = (const float*)d_in[4];
    const float* Wk = (const float*)d_in[5];
    const float* bk = (const float*)d_in[6];
    const float* Wv = (const float*)d_in[7];
    const float* bv = (const float*)d_in[8];
    const float* lag = (const float*)d_in[9];
    const float* lab = (const float*)d_in[10];
    const float* lfg = (const float*)d_in[11];
    const float* lfb = (const float*)d_in[12];
    const float* W1 = (const float*)d_in[13];
    const float* b1 = (const float*)d_in[14];
    const float* W2 = (const float*)d_in[15];
    const float* b2 = (const float*)d_in[16];
    const float* llg = (const float*)d_in[17];
    const float* llb = (const float*)d_in[18];
    float* out = (float*)d_out;
    float* ws = (float*)d_ws;

    hipFuncSetAttribute((const void*)attn4_kernel,
                        hipFuncAttributeMaxDynamicSharedMemorySize,
                        ATTN_LDS_BYTES);

    // workspace ~241.4 MB (262.45 MB proven safe):
    // tgt f32 | aout f32 | srcb | qb kb vb (contiguous, for fused QKV) | lnb |
    // WqkvT [NB][3][512][512] | W1T | W2T | masks
    const size_t n = (size_t)BL * DD;
    float* tgt = ws;
    float* aout = ws + n;
    ushort_t* srcb = (ushort_t*)(ws + 2 * n);
    ushort_t* qb = srcb + n;
    ushort_t* kb = qb + n;
    ushort_t* vb = kb + n;
    ushort_t* lnb = vb + n;          // dedicated: read by gemm_qkv z=0 while z=2 writes vb
    ushort_t* WqkvT = lnb + n;
    ushort_t* W1T = WqkvT + (size_t)NBLK * 3 * DD * DD;
    ushort_t* W2T = W1T + (size_t)NBLK * DD * DD;
    float* tlf = (float*)(W2T + (size_t)NBLK * DD * DD);
    float* keepf = tlf + BL;
    float* kmf = keepf + BL;
    ushort_t* hb = qb;               // FFN1 out: qb dead after attention

    mask_kernel<<<(BL + 255) / 256, 256, 0, stream>>>(log_seqs, entire, tlf, keepf, kmf);
    init_target<<<BL, 256, 0, stream>>>(seqs_embs, keepf, tgt);
    src_kernel<<<BL, 256, 0, stream>>>(seqs_embs, tlf, srcb);
    dim3 tg(16, 16, NBLK);
    wtrans_kernel<<<tg, 256, 0, stream>>>(Wq, WqkvT, (size_t)3 * DD * DD, 0);
    wtrans_kernel<<<tg, 256, 0, stream>>>(Wk, WqkvT, (size_t)3 * DD * DD, (size_t)DD * DD);
    wtrans_kernel<<<tg, 256, 0, stream>>>(Wv, WqkvT, (size_t)3 * DD * DD, (size_t)2 * DD * DD);
    wtrans_kernel<<<tg, 256, 0, stream>>>(W1, W1T, (size_t)DD * DD, 0);
    wtrans_kernel<<<tg, 256, 0, stream>>>(W2, W2T, (size_t)DD * DD, 0);

    dim3 gg(BL / 128, DD / 128);
    dim3 gq(BL / 128, DD / 128, 3);
    for (int i = 0; i < NBLK; i++) {
        size_t wo = (size_t)i * DD * DD;
        // lnb = bf16(LN(tgt, ln_attn))
        ln_kernel<<<BL, 256, 0, stream>>>(tgt, nullptr, nullptr, lnb,
                                          lag + i * DD, lab + i * DD, nullptr);
        // fused q,k,v projections -> qb,kb,vb (bf16)
        gemm_qkv<<<gq, 256, 0, stream>>>(lnb, srcb, WqkvT + (size_t)i * 3 * DD * DD,
                                         bq + i * DD, bk + i * DD, bv + i * DD, qb);
        // attention (MFMA) -> aout fp32
        attn4_kernel<<<BB * HH, 256, ATTN_LDS_BYTES, stream>>>(qb, kb, vb, kmf, aout);
        // tgt = LN(aout (+tgt)), bf16 copy to lnb
        ln_kernel<<<BL, 256, 0, stream>>>(aout, (i == 0) ? nullptr : tgt, tgt, lnb,
                                          lfg + i * DD, lfb + i * DD, nullptr);
        // hb = bf16(relu(lnb @ W1 + b1))
        gemm_mfma<<<gg, 256, 0, stream>>>(lnb, W1T + wo, b1 + i * DD, nullptr, hb,
                                          nullptr, 1, BL, DD, DD);
        // tgt = (tgt + hb @ W2 + b2) * keep
        gemm_mfma<<<gg, 256, 0, stream>>>(hb, W2T + wo, b2 + i * DD, tgt, nullptr,
                                          keepf, 2, BL, DD, DD);
    }
    ln_kernel<<<BL, 256, 0, stream>>>(tgt, nullptr, out, nullptr, llg, llb, keepf);
}

// Round 7
// 802.998 us; speedup vs baseline: 2.5916x; 2.5916x over previous
//
#include <hip/hip_runtime.h>
#include <hip/hip_bf16.h>

#define BB 128
#define LL 200
#define DD 512
#define HH 8
#define DK 64
#define NBLK 2
#define BL (BB*LL)

typedef unsigned short ushort_t;
typedef unsigned int uint_t;
typedef __attribute__((ext_vector_type(8))) short short8;
typedef __attribute__((ext_vector_type(4))) float f32x4;

__device__ inline ushort_t f2b(float x) {
    unsigned u = __float_as_uint(x);
    unsigned r = (u + 0x7FFF + ((u >> 16) & 1)) >> 16;
    return (ushort_t)r;
}

__device__ inline void gload16(const void* g, void* l) {
    __builtin_amdgcn_global_load_lds((const __attribute__((address_space(1))) void*)g,
                                     (__attribute__((address_space(3))) void*)l,
                                     16, 0, 0);
}

// ---------------- masks ----------------
__global__ __launch_bounds__(256) void mask_kernel(const int* __restrict__ logs,
                                                   const int* __restrict__ entire,
                                                   float* __restrict__ tlf,
                                                   float* __restrict__ keepf,
                                                   float* __restrict__ kmf) {
    int i = blockIdx.x * 256 + threadIdx.x;
    if (i < BL) {
        float t = (logs[i] == 0) ? 1.f : 0.f;
        tlf[i] = t;
        keepf[i] = 1.f - t;
        kmf[i] = (logs[i] == 0 && entire[i] != 0) ? 1.f : 0.f;
    }
}

// target = seqs_embs * keep
__global__ __launch_bounds__(256) void init_target(const float* __restrict__ emb,
                                                   const float* __restrict__ keepf,
                                                   float* __restrict__ tgt) {
    int row = blockIdx.x;
    int t = threadIdx.x;
    float kf = keepf[row];
    size_t base = (size_t)row * DD;
    tgt[base + t] = emb[base + t] * kf;
    tgt[base + t + 256] = emb[base + t + 256] * kf;
}

// src_bf16 = emb * tl
__global__ __launch_bounds__(256) void src_kernel(const float* __restrict__ emb,
                                                  const float* __restrict__ tlf,
                                                  ushort_t* __restrict__ srcb) {
    int row = blockIdx.x;
    int t = threadIdx.x;
    float s = tlf[row];
    size_t base = (size_t)row * DD;
    srcb[base + t] = f2b(emb[base + t] * s);
    srcb[base + t + 256] = f2b(emb[base + t + 256] * s);
}

// weight transpose + bf16: Wt[n][k] = W[k][n]; dst = Wt + z*zstride + base
__global__ __launch_bounds__(256) void wtrans_kernel(const float* __restrict__ W,
                                                     ushort_t* __restrict__ Wt,
                                                     size_t zstride, size_t base) {
    __shared__ float ts[32][33];
    int tx = threadIdx.x & 31, ty = threadIdx.x >> 5;
    int bx = blockIdx.x * 32, by = blockIdx.y * 32;
    const float* Wm = W + (size_t)blockIdx.z * DD * DD;
    ushort_t* Wtm = Wt + (size_t)blockIdx.z * zstride + base;
    #pragma unroll
    for (int i = 0; i < 4; i++) {
        int r = ty + i * 8;
        ts[r][tx] = Wm[(size_t)(by + r) * DD + bx + tx];
    }
    __syncthreads();
    #pragma unroll
    for (int i = 0; i < 4; i++) {
        int r = ty + i * 8;
        Wtm[(size_t)(bx + r) * DD + by + tx] = f2b(ts[tx][r]);
    }
}

// ---------------- layernorm ----------------
__global__ __launch_bounds__(256) void ln_kernel(const float* __restrict__ x,
                                                 const float* __restrict__ addx,
                                                 float* __restrict__ outf,
                                                 ushort_t* __restrict__ outb,
                                                 const float* __restrict__ g,
                                                 const float* __restrict__ bt,
                                                 const float* __restrict__ keepf) {
    int row = blockIdx.x;
    int t = threadIdx.x;
    size_t base = (size_t)row * DD;
    float v0 = x[base + t], v1 = x[base + t + 256];
    if (addx) { v0 += addx[base + t]; v1 += addx[base + t + 256]; }
    float s = v0 + v1, sq = v0 * v0 + v1 * v1;
    #pragma unroll
    for (int off = 32; off; off >>= 1) {
        s += __shfl_xor(s, off);
        sq += __shfl_xor(sq, off);
    }
    __shared__ float rs[4], rq[4];
    int wid = t >> 6, lane = t & 63;
    if (lane == 0) { rs[wid] = s; rq[wid] = sq; }
    __syncthreads();
    s = rs[0] + rs[1] + rs[2] + rs[3];
    sq = rq[0] + rq[1] + rq[2] + rq[3];
    float mean = s * (1.f / DD);
    float var = sq * (1.f / DD) - mean * mean;
    float rstd = rsqrtf(fmaxf(var, 0.f) + 1e-8f);
    float kf = keepf ? keepf[row] : 1.f;
    float o0 = ((v0 - mean) * rstd * g[t] + bt[t]) * kf;
    float o1 = ((v1 - mean) * rstd * g[t + 256] + bt[t + 256]) * kf;
    if (outf) { outf[base + t] = o0; outf[base + t + 256] = o1; }
    if (outb) { outb[base + t] = f2b(o0); outb[base + t + 256] = f2b(o1); }
}

// ---------------- bf16 MFMA GEMM: C = A @ Wt^T + bias ----------------
// mode 1: Cb = bf16(relu(acc+bias)) ; mode 2: Cf = (Cf+acc+bias)*keepf
__global__ __launch_bounds__(256) void gemm_mfma(const ushort_t* __restrict__ A,
                                                 const ushort_t* __restrict__ Bt,
                                                 const float* __restrict__ bias,
                                                 float* __restrict__ Cf,
                                                 ushort_t* __restrict__ Cb,
                                                 const float* __restrict__ keepf,
                                                 int mode, int M, int N, int K) {
    __shared__ ushort_t sA[128 * 32];
    __shared__ ushort_t sB[128 * 32];
    int t = threadIdx.x;
    int w = t >> 6, lane = t & 63;
    int wm = w & 1, wn = w >> 1;
    int m0 = blockIdx.x * 128, n0 = blockIdx.y * 128;
    int lr = lane & 15, lq = lane >> 4;

    f32x4 acc[4][4] = {};

    for (int k0 = 0; k0 < K; k0 += 32) {
        #pragma unroll
        for (int r = 0; r < 2; r++) {
            int e = (r * 256 + t) * 8;
            int row = e >> 5, col = e & 31;
            gload16(A + (size_t)(m0 + row) * K + k0 + col, sA + (r * 256 + w * 64) * 8);
            gload16(Bt + (size_t)(n0 + row) * K + k0 + col, sB + (r * 256 + w * 64) * 8);
        }
        __syncthreads();

        short8 af[4], bf[4];
        #pragma unroll
        for (int mt = 0; mt < 4; mt++)
            af[mt] = *(const short8*)(sA + (wm * 64 + mt * 16 + lr) * 32 + lq * 8);
        #pragma unroll
        for (int nt = 0; nt < 4; nt++)
            bf[nt] = *(const short8*)(sB + (wn * 64 + nt * 16 + lr) * 32 + lq * 8);
        #pragma unroll
        for (int mt = 0; mt < 4; mt++)
            #pragma unroll
            for (int nt = 0; nt < 4; nt++)
                acc[mt][nt] = __builtin_amdgcn_mfma_f32_16x16x32_bf16(af[mt], bf[nt], acc[mt][nt], 0, 0, 0);
        __syncthreads();
    }

    #pragma unroll
    for (int nt = 0; nt < 4; nt++) {
        int col = n0 + wn * 64 + nt * 16 + lr;
        float bv = bias[col];
        #pragma unroll
        for (int mt = 0; mt < 4; mt++) {
            int rowb = m0 + wm * 64 + mt * 16 + lq * 4;
            #pragma unroll
            for (int r = 0; r < 4; r++) {
                int row = rowb + r;
                float o = acc[mt][nt][r] + bv;
                size_t idx = (size_t)row * N + col;
                if (mode == 1) {
                    Cb[idx] = f2b(fmaxf(o, 0.f));
                } else {
                    float kf = keepf[row];
                    Cf[idx] = (Cf[idx] + o) * kf;
                }
            }
        }
    }
}

// ---------------- fused Q/K/V projection: grid (200, 4, 3) ----------------
__global__ __launch_bounds__(256) void gemm_qkv(const ushort_t* __restrict__ Aq,
                                                const ushort_t* __restrict__ Akv,
                                                const ushort_t* __restrict__ Bqkv,
                                                const float* __restrict__ bq,
                                                const float* __restrict__ bk,
                                                const float* __restrict__ bv,
                                                ushort_t* __restrict__ qkv) {
    __shared__ ushort_t sA[128 * 32];
    __shared__ ushort_t sB[128 * 32];
    int z = blockIdx.z;
    const ushort_t* A = (z == 0) ? Aq : Akv;
    const ushort_t* Bt = Bqkv + (size_t)z * DD * DD;
    const float* bias = (z == 0) ? bq : (z == 1) ? bk : bv;
    ushort_t* C = qkv + (size_t)z * BL * DD;

    int t = threadIdx.x;
    int w = t >> 6, lane = t & 63;
    int wm = w & 1, wn = w >> 1;
    int m0 = blockIdx.x * 128, n0 = blockIdx.y * 128;
    int lr = lane & 15, lq = lane >> 4;

    f32x4 acc[4][4] = {};

    for (int k0 = 0; k0 < DD; k0 += 32) {
        #pragma unroll
        for (int r = 0; r < 2; r++) {
            int e = (r * 256 + t) * 8;
            int row = e >> 5, col = e & 31;
            gload16(A + (size_t)(m0 + row) * DD + k0 + col, sA + (r * 256 + w * 64) * 8);
            gload16(Bt + (size_t)(n0 + row) * DD + k0 + col, sB + (r * 256 + w * 64) * 8);
        }
        __syncthreads();

        short8 af[4], bf[4];
        #pragma unroll
        for (int mt = 0; mt < 4; mt++)
            af[mt] = *(const short8*)(sA + (wm * 64 + mt * 16 + lr) * 32 + lq * 8);
        #pragma unroll
        for (int nt = 0; nt < 4; nt++)
            bf[nt] = *(const short8*)(sB + (wn * 64 + nt * 16 + lr) * 32 + lq * 8);
        #pragma unroll
        for (int mt = 0; mt < 4; mt++)
            #pragma unroll
            for (int nt = 0; nt < 4; nt++)
                acc[mt][nt] = __builtin_amdgcn_mfma_f32_16x16x32_bf16(af[mt], bf[nt], acc[mt][nt], 0, 0, 0);
        __syncthreads();
    }

    #pragma unroll
    for (int nt = 0; nt < 4; nt++) {
        int col = n0 + wn * 64 + nt * 16 + lr;
        float bv2 = bias[col];
        #pragma unroll
        for (int mt = 0; mt < 4; mt++) {
            int rowb = m0 + wm * 64 + mt * 16 + lq * 4;
            #pragma unroll
            for (int r = 0; r < 4; r++) {
                int row = rowb + r;
                C[(size_t)row * DD + col] = f2b(acc[mt][nt][r] + bv2);
            }
        }
    }
}

// ---------------- attention v4b: MFMA, wg per (b,h), 62.7 KB LDS, 2 blocks/CU ----
// LDS: sKP (K[208][72] 29,952 B, later P[64][232] 29,696 B) | sVt[64][232] 29,696 B
//      | floats: kms[256], redm[256], reds[256]  => 62,720 B total
// ALL register arrays statically indexed (round-6 scratch-spill lesson).
// Wave 3's nt>=1 K-fragment reads land past the 208 K rows (inside the LDS
// allocation, garbage) — masking REPLACES those scores with -1e9, so garbage
// (even NaN) never propagates.
#define ATTN_LDS_BYTES 62720
__global__ __launch_bounds__(256, 2) void attn4_kernel(const ushort_t* __restrict__ q,
                                                       const ushort_t* __restrict__ k,
                                                       const ushort_t* __restrict__ v,
                                                       const float* __restrict__ kmf,
                                                       float* __restrict__ xout) {
    extern __shared__ ushort_t su[];
    ushort_t* sKP = su;                 // K: [208][72] / P: [64][232]
    ushort_t* sVt = su + 14976;         // [64][232]
    float* fl = (float*)(su + 29824);
    float* kms = fl;                    // [256]
    float* redm = fl + 256;             // [256]
    float* reds = fl + 512;             // [256]

    int t = threadIdx.x;
    int b = blockIdx.x >> 3, h = blockIdx.x & 7;
    int w = t >> 6, lane = t & 63;
    int lr = lane & 15, lq = lane >> 4;

    const ushort_t* kg = k + (size_t)b * LL * DD + h * DK;
    const ushort_t* vg = v + (size_t)b * LL * DD + h * DK;
    const ushort_t* qg = q + (size_t)b * LL * DD + h * DK;
    float* og = xout + (size_t)b * LL * DD + h * DK;

    // stage V^T once: word (d*116 + tt) holds keys {2tt, 2tt+1} for dim d
    for (int idx = t; idx < 1024; idx += 256) {
        int s = idx >> 7, tt = idx & 127;
        if (tt < 116) {
            uint_t outw[8];
            if (tt < 100) {
                int j0 = tt * 2;
                uint4 a = *(const uint4*)(vg + (size_t)j0 * DD + s * 8);
                uint4 c = *(const uint4*)(vg + (size_t)(j0 + 1) * DD + s * 8);
                uint_t av[4] = {a.x, a.y, a.z, a.w};
                uint_t cv[4] = {c.x, c.y, c.z, c.w};
                #pragma unroll
                for (int i = 0; i < 8; i++) {
                    uint_t lo = (av[i >> 1] >> ((i & 1) * 16)) & 0xFFFFu;
                    uint_t hi = (cv[i >> 1] >> ((i & 1) * 16)) & 0xFFFFu;
                    outw[i] = lo | (hi << 16);
                }
            } else {
                #pragma unroll
                for (int i = 0; i < 8; i++) outw[i] = 0;
            }
            #pragma unroll
            for (int i = 0; i < 8; i++)
                ((uint_t*)sVt)[(s * 8 + i) * 116 + tt] = outw[i];
        }
    }
    kms[t] = (t < LL) ? kmf[b * LL + t] : 0.f;
    // no barrier needed yet: first use of sVt/kms is after the qtile-0 barrier

    for (int qt = 0; qt < 4; qt++) {
        int q0 = qt * 64;

        // re-stage K [200][64] -> sKP pitch 72 (P overwrote it last qtile), zero 200..207
        for (int idx = t; idx < 1600; idx += 256) {
            int row = idx >> 3, seg = idx & 7;
            *(uint4*)(sKP + row * 72 + seg * 8) = *(const uint4*)(kg + (size_t)row * DD + seg * 8);
        }
        if (t < 64) {
            int row = 200 + (t >> 3), seg = t & 7;
            uint4 z4 = {0, 0, 0, 0};
            *(uint4*)(sKP + row * 72 + seg * 8) = z4;
        }
        // Q fragments direct from global (A-layout = natural row chunks)
        short8 af[2][4];
        #pragma unroll
        for (int ks = 0; ks < 2; ks++)
            #pragma unroll
            for (int mt = 0; mt < 4; mt++) {
                int grow = q0 + mt * 16 + lr;
                if (grow > LL - 1) grow = LL - 1;
                af[ks][mt] = *(const short8*)(qg + (size_t)grow * DD + ks * 32 + lq * 8);
            }
        __syncthreads();

        // S = Q @ K^T ; wave w covers keys w*64..w*64+63 (fully static unroll)
        f32x4 accS[4][4] = {};
        #pragma unroll
        for (int ks = 0; ks < 2; ks++) {
            short8 bf[4];
            #pragma unroll
            for (int nt = 0; nt < 4; nt++)
                bf[nt] = *(const short8*)(sKP + (w * 64 + nt * 16 + lr) * 72 + ks * 32 + lq * 8);
            #pragma unroll
            for (int nt = 0; nt < 4; nt++)
                #pragma unroll
                for (int mt = 0; mt < 4; mt++)
                    accS[mt][nt] = __builtin_amdgcn_mfma_f32_16x16x32_bf16(af[ks][mt], bf[nt], accS[mt][nt], 0, 0, 0);
        }

        // mask + scale + per-wave row max
        float km[4];
        #pragma unroll
        for (int nt = 0; nt < 4; nt++) km[nt] = kms[w * 64 + nt * 16 + lr];
        float rmax[4][4];
        #pragma unroll
        for (int mt = 0; mt < 4; mt++) {
            #pragma unroll
            for (int r = 0; r < 4; r++) {
                int qrow = q0 + mt * 16 + lq * 4 + r;
                float m = -1e9f;
                #pragma unroll
                for (int nt = 0; nt < 4; nt++) {
                    int j = w * 64 + nt * 16 + lr;
                    bool ok = (j <= qrow) && (km[nt] != 0.f);
                    float s = ok ? accS[mt][nt][r] * 0.125f : -1e9f;
                    accS[mt][nt][r] = s;
                    m = fmaxf(m, s);
                }
                #pragma unroll
                for (int off = 1; off < 16; off <<= 1)
                    m = fmaxf(m, __shfl_xor(m, off));
                rmax[mt][r] = m;
            }
        }
        if (lr == 0) {
            #pragma unroll
            for (int mt = 0; mt < 4; mt++)
                #pragma unroll
                for (int r = 0; r < 4; r++)
                    redm[w * 64 + mt * 16 + lq * 4 + r] = rmax[mt][r];
        }
        __syncthreads();

        // exp + per-wave row sum
        float gmx[4][4], rsum[4][4];
        #pragma unroll
        for (int mt = 0; mt < 4; mt++) {
            #pragma unroll
            for (int r = 0; r < 4; r++) {
                int row = mt * 16 + lq * 4 + r;
                float gm = fmaxf(fmaxf(redm[row], redm[64 + row]),
                                 fmaxf(redm[128 + row], redm[192 + row]));
                gmx[mt][r] = gm;
                float ps = 0.f;
                #pragma unroll
                for (int nt = 0; nt < 4; nt++) {
                    float e = __expf(accS[mt][nt][r] - gm);
                    accS[mt][nt][r] = e;
                    ps += e;
                }
                #pragma unroll
                for (int off = 1; off < 16; off <<= 1)
                    ps += __shfl_xor(ps, off);
                rsum[mt][r] = ps;
            }
        }
        if (lr == 0) {
            #pragma unroll
            for (int mt = 0; mt < 4; mt++)
                #pragma unroll
                for (int r = 0; r < 4; r++)
                    reds[w * 64 + mt * 16 + lq * 4 + r] = rsum[mt][r];
        }
        __syncthreads();

        // normalize -> bf16 P over the K region (K frag reads all completed pre-barrier)
        #pragma unroll
        for (int mt = 0; mt < 4; mt++) {
            #pragma unroll
            for (int r = 0; r < 4; r++) {
                int row = mt * 16 + lq * 4 + r;
                float tot = reds[row] + reds[64 + row] + reds[128 + row] + reds[192 + row];
                float inv = (gmx[mt][r] < -5e8f) ? 0.f : 1.f / tot;
                #pragma unroll
                for (int nt = 0; nt < 4; nt++) {
                    int col = w * 64 + nt * 16 + lr;
                    if (col < 224)
                        sKP[row * 232 + col] = f2b(accS[mt][nt][r] * inv);
                }
            }
        }
        __syncthreads();

        // O = P @ V ; wave w covers d-tile w*16..w*16+15 ; keys 0..223 (224+ not stored)
        f32x4 accO[4] = {};
        #pragma unroll
        for (int ks2 = 0; ks2 < 7; ks2++) {
            short8 bfv = *(const short8*)(sVt + (w * 16 + lr) * 232 + ks2 * 32 + lq * 8);
            #pragma unroll
            for (int mt = 0; mt < 4; mt++) {
                short8 afp = *(const short8*)(sKP + (mt * 16 + lr) * 232 + ks2 * 32 + lq * 8);
                accO[mt] = __builtin_amdgcn_mfma_f32_16x16x32_bf16(afp, bfv, accO[mt], 0, 0, 0);
            }
        }
        #pragma unroll
        for (int mt = 0; mt < 4; mt++) {
            #pragma unroll
            for (int r = 0; r < 4; r++) {
                int row = q0 + mt * 16 + lq * 4 + r;
                if (row < LL)
                    og[(size_t)row * DD + w * 16 + lr] = accO[mt][r];
            }
        }
        __syncthreads();   // P reads done before next qtile re-stages K
    }
}

extern "C" void kernel_launch(void* const* d_in, const int* in_sizes, int n_in,
                              void* d_out, int out_size, void* d_ws, size_t ws_size,
                              hipStream_t stream) {
    const int* log_seqs = (const int*)d_in[0];
    const float* seqs_embs = (const float*)d_in[1];
    const int* entire = (const int*)d_in[2];
    const float* Wq = (const float*)d_in[3];
    const float* bq = (const float*)d_in[4];
    const float* Wk = (const float*)d_in[5];
    const float* bk = (const float*)d_in[6];
    const float* Wv = (const float*)d_in[7];
    const float* bv = (const float*)d_in[8];
    const float* lag = (const float*)d_in[9];
    const float* lab = (const float*)d_in[10];
    const float* lfg = (const float*)d_in[11];
    const float* lfb = (const float*)d_in[12];
    const float* W1 = (const float*)d_in[13];
    const float* b1 = (const float*)d_in[14];
    const float* W2 = (const float*)d_in[15];
    const float* b2 = (const float*)d_in[16];
    const float* llg = (const float*)d_in[17];
    const float* llb = (const float*)d_in[18];
    float* out = (float*)d_out;
    float* ws = (float*)d_ws;

    hipFuncSetAttribute((const void*)attn4_kernel,
                        hipFuncAttributeMaxDynamicSharedMemorySize,
                        ATTN_LDS_BYTES);

    // workspace ~241.4 MB (262.45 MB proven safe)
    const size_t n = (size_t)BL * DD;
    float* tgt = ws;
    float* aout = ws + n;
    ushort_t* srcb = (ushort_t*)(ws + 2 * n);
    ushort_t* qb = srcb + n;
    ushort_t* kb = qb + n;
    ushort_t* vb = kb + n;
    ushort_t* lnb = vb + n;          // dedicated: read by gemm_qkv z=0 while z=2 writes vb
    ushort_t* WqkvT = lnb + n;
    ushort_t* W1T = WqkvT + (size_t)NBLK * 3 * DD * DD;
    ushort_t* W2T = W1T + (size_t)NBLK * DD * DD;
    float* tlf = (float*)(W2T + (size_t)NBLK * DD * DD);
    float* keepf = tlf + BL;
    float* kmf = keepf + BL;
    ushort_t* hb = qb;               // FFN1 out: qb dead after attention

    mask_kernel<<<(BL + 255) / 256, 256, 0, stream>>>(log_seqs, entire, tlf, keepf, kmf);
    init_target<<<BL, 256, 0, stream>>>(seqs_embs, keepf, tgt);
    src_kernel<<<BL, 256, 0, stream>>>(seqs_embs, tlf, srcb);
    dim3 tg(16, 16, NBLK);
    wtrans_kernel<<<tg, 256, 0, stream>>>(Wq, WqkvT, (size_t)3 * DD * DD, 0);
    wtrans_kernel<<<tg, 256, 0, stream>>>(Wk, WqkvT, (size_t)3 * DD * DD, (size_t)DD * DD);
    wtrans_kernel<<<tg, 256, 0, stream>>>(Wv, WqkvT, (size_t)3 * DD * DD, (size_t)2 * DD * DD);
    wtrans_kernel<<<tg, 256, 0, stream>>>(W1, W1T, (size_t)DD * DD, 0);
    wtrans_kernel<<<tg, 256, 0, stream>>>(W2, W2T, (size_t)DD * DD, 0);

    dim3 gg(BL / 128, DD / 128);
    dim3 gq(BL / 128, DD / 128, 3);
    for (int i = 0; i < NBLK; i++) {
        size_t wo = (size_t)i * DD * DD;
        // lnb = bf16(LN(tgt, ln_attn))
        ln_kernel<<<BL, 256, 0, stream>>>(tgt, nullptr, nullptr, lnb,
                                          lag + i * DD, lab + i * DD, nullptr);
        // fused q,k,v projections -> qb,kb,vb (bf16)
        gemm_qkv<<<gq, 256, 0, stream>>>(lnb, srcb, WqkvT + (size_t)i * 3 * DD * DD,
                                         bq + i * DD, bk + i * DD, bv + i * DD, qb);
        // attention (MFMA) -> aout fp32
        attn4_kernel<<<BB * HH, 256, ATTN_LDS_BYTES, stream>>>(qb, kb, vb, kmf, aout);
        // tgt = LN(aout (+tgt)), bf16 copy to lnb
        ln_kernel<<<BL, 256, 0, stream>>>(aout, (i == 0) ? nullptr : tgt, tgt, lnb,
                                          lfg + i * DD, lfb + i * DD, nullptr);
        // hb = bf16(relu(lnb @ W1 + b1))
        gemm_mfma<<<gg, 256, 0, stream>>>(lnb, W1T + wo, b1 + i * DD, nullptr, hb,
                                          nullptr, 1, BL, DD, DD);
        // tgt = (tgt + hb @ W2 + b2) * keep
        gemm_mfma<<<gg, 256, 0, stream>>>(hb, W2T + wo, b2 + i * DD, tgt, nullptr,
                                          keepf, 2, BL, DD, DD);
    }
    ln_kernel<<<BL, 256, 0, stream>>>(tgt, nullptr, out, nullptr, llg, llb, keepf);
}

// Round 8
// 752.733 us; speedup vs baseline: 2.7647x; 1.0668x over previous
//
#include <hip/hip_runtime.h>
#include <hip/hip_bf16.h>

#define BB 128
#define LL 200
#define DD 512
#define HH 8
#define DK 64
#define NBLK 2
#define BL (BB*LL)

typedef unsigned short ushort_t;
typedef unsigned int uint_t;
typedef __attribute__((ext_vector_type(8))) short short8;
typedef __attribute__((ext_vector_type(4))) float f32x4;

__device__ inline ushort_t f2b(float x) {
    unsigned u = __float_as_uint(x);
    unsigned r = (u + 0x7FFF + ((u >> 16) & 1)) >> 16;
    return (ushort_t)r;
}

__device__ inline void gload16(const void* g, void* l) {
    __builtin_amdgcn_global_load_lds((const __attribute__((address_space(1))) void*)g,
                                     (__attribute__((address_space(3))) void*)l,
                                     16, 0, 0);
}

// ---------------- masks (keepf, kmf) ----------------
__global__ __launch_bounds__(256) void mask_kernel(const int* __restrict__ logs,
                                                   const int* __restrict__ entire,
                                                   float* __restrict__ keepf,
                                                   float* __restrict__ kmf) {
    int i = blockIdx.x * 256 + threadIdx.x;
    if (i < BL) {
        keepf[i] = (logs[i] == 0) ? 0.f : 1.f;
        kmf[i] = (logs[i] == 0 && entire[i] != 0) ? 1.f : 0.f;
    }
}

// fused: tgt = emb*keep (fp32) ; srcb = bf16(emb*tl) — one emb read
__global__ __launch_bounds__(256) void prep_kernel(const int* __restrict__ logs,
                                                   const float* __restrict__ emb,
                                                   float* __restrict__ tgt,
                                                   ushort_t* __restrict__ srcb) {
    int row = blockIdx.x;
    int t = threadIdx.x;
    bool src = (logs[row] == 0);
    float kf = src ? 0.f : 1.f, sf = src ? 1.f : 0.f;
    size_t base = (size_t)row * DD;
    float e0 = emb[base + t], e1 = emb[base + t + 256];
    tgt[base + t] = e0 * kf;
    tgt[base + t + 256] = e1 * kf;
    srcb[base + t] = f2b(e0 * sf);
    srcb[base + t + 256] = f2b(e1 * sf);
}

// fused weight transpose + bf16 for all 10 matrices: grid (16,16,10)
__global__ __launch_bounds__(256) void wtrans10_kernel(const float* __restrict__ Wq,
                                                       const float* __restrict__ Wk,
                                                       const float* __restrict__ Wv,
                                                       const float* __restrict__ W1,
                                                       const float* __restrict__ W2,
                                                       ushort_t* __restrict__ WqkvT,
                                                       ushort_t* __restrict__ W1T,
                                                       ushort_t* __restrict__ W2T) {
    __shared__ float ts[32][33];
    int tx = threadIdx.x & 31, ty = threadIdx.x >> 5;
    int bx = blockIdx.x * 32, by = blockIdx.y * 32;
    int z = blockIdx.z;
    const float* Wm;
    ushort_t* Wtm;
    if (z < 6) {
        int i = z / 3, j = z - 3 * i;
        const float* src = (j == 0) ? Wq : (j == 1) ? Wk : Wv;
        Wm = src + (size_t)i * DD * DD;
        Wtm = WqkvT + (size_t)z * DD * DD;
    } else if (z < 8) {
        Wm = W1 + (size_t)(z - 6) * DD * DD;
        Wtm = W1T + (size_t)(z - 6) * DD * DD;
    } else {
        Wm = W2 + (size_t)(z - 8) * DD * DD;
        Wtm = W2T + (size_t)(z - 8) * DD * DD;
    }
    #pragma unroll
    for (int i = 0; i < 4; i++) {
        int r = ty + i * 8;
        ts[r][tx] = Wm[(size_t)(by + r) * DD + bx + tx];
    }
    __syncthreads();
    #pragma unroll
    for (int i = 0; i < 4; i++) {
        int r = ty + i * 8;
        Wtm[(size_t)(bx + r) * DD + by + tx] = f2b(ts[tx][r]);
    }
}

// ---------------- layernorm ----------------
__global__ __launch_bounds__(256) void ln_kernel(const float* __restrict__ x,
                                                 const float* __restrict__ addx,
                                                 float* __restrict__ outf,
                                                 ushort_t* __restrict__ outb,
                                                 const float* __restrict__ g,
                                                 const float* __restrict__ bt,
                                                 const float* __restrict__ keepf) {
    int row = blockIdx.x;
    int t = threadIdx.x;
    size_t base = (size_t)row * DD;
    float v0 = x[base + t], v1 = x[base + t + 256];
    if (addx) { v0 += addx[base + t]; v1 += addx[base + t + 256]; }
    float s = v0 + v1, sq = v0 * v0 + v1 * v1;
    #pragma unroll
    for (int off = 32; off; off >>= 1) {
        s += __shfl_xor(s, off);
        sq += __shfl_xor(sq, off);
    }
    __shared__ float rs[4], rq[4];
    int wid = t >> 6, lane = t & 63;
    if (lane == 0) { rs[wid] = s; rq[wid] = sq; }
    __syncthreads();
    s = rs[0] + rs[1] + rs[2] + rs[3];
    sq = rq[0] + rq[1] + rq[2] + rq[3];
    float mean = s * (1.f / DD);
    float var = sq * (1.f / DD) - mean * mean;
    float rstd = rsqrtf(fmaxf(var, 0.f) + 1e-8f);
    float kf = keepf ? keepf[row] : 1.f;
    float o0 = ((v0 - mean) * rstd * g[t] + bt[t]) * kf;
    float o1 = ((v1 - mean) * rstd * g[t + 256] + bt[t + 256]) * kf;
    if (outf) { outf[base + t] = o0; outf[base + t + 256] = o1; }
    if (outb) { outb[base + t] = f2b(o0); outb[base + t + 256] = f2b(o1); }
}

// ---------------- bf16 MFMA GEMM, BK=64 via two 128x32 sub-tiles ----------------
// (flat 128x64 tile would alias all lr lanes onto 4 banks; two pitch-32-ushort
//  sub-tiles keep the proven m97 bank pattern AND global_load_lds contiguity)
// mode 1: Cb = bf16(relu(acc+bias)) ; mode 2: Cf = (Cf+acc+bias)*keepf
__global__ __launch_bounds__(256) void gemm_mfma(const ushort_t* __restrict__ A,
                                                 const ushort_t* __restrict__ Bt,
                                                 const float* __restrict__ bias,
                                                 float* __restrict__ Cf,
                                                 ushort_t* __restrict__ Cb,
                                                 const float* __restrict__ keepf,
                                                 int mode, int M, int N, int K) {
    __shared__ ushort_t sA[2][128 * 32];
    __shared__ ushort_t sB[2][128 * 32];
    int t = threadIdx.x;
    int w = t >> 6, lane = t & 63;
    int wm = w & 1, wn = w >> 1;
    int m0 = blockIdx.x * 128, n0 = blockIdx.y * 128;
    int lr = lane & 15, lq = lane >> 4;

    f32x4 acc[4][4] = {};

    for (int k0 = 0; k0 < K; k0 += 64) {
        #pragma unroll
        for (int hh = 0; hh < 2; hh++) {
            #pragma unroll
            for (int r = 0; r < 2; r++) {
                int e = (r * 256 + t) * 8;
                int row = e >> 5, col = e & 31;
                gload16(A + (size_t)(m0 + row) * K + k0 + hh * 32 + col,
                        sA[hh] + (r * 256 + w * 64) * 8);
                gload16(Bt + (size_t)(n0 + row) * K + k0 + hh * 32 + col,
                        sB[hh] + (r * 256 + w * 64) * 8);
            }
        }
        __syncthreads();

        #pragma unroll
        for (int hh = 0; hh < 2; hh++) {
            short8 af[4], bf[4];
            #pragma unroll
            for (int mt = 0; mt < 4; mt++)
                af[mt] = *(const short8*)(sA[hh] + (wm * 64 + mt * 16 + lr) * 32 + lq * 8);
            #pragma unroll
            for (int nt = 0; nt < 4; nt++)
                bf[nt] = *(const short8*)(sB[hh] + (wn * 64 + nt * 16 + lr) * 32 + lq * 8);
            #pragma unroll
            for (int mt = 0; mt < 4; mt++)
                #pragma unroll
                for (int nt = 0; nt < 4; nt++)
                    acc[mt][nt] = __builtin_amdgcn_mfma_f32_16x16x32_bf16(af[mt], bf[nt], acc[mt][nt], 0, 0, 0);
        }
        __syncthreads();
    }

    #pragma unroll
    for (int nt = 0; nt < 4; nt++) {
        int col = n0 + wn * 64 + nt * 16 + lr;
        float bv = bias[col];
        #pragma unroll
        for (int mt = 0; mt < 4; mt++) {
            int rowb = m0 + wm * 64 + mt * 16 + lq * 4;
            #pragma unroll
            for (int r = 0; r < 4; r++) {
                int row = rowb + r;
                float o = acc[mt][nt][r] + bv;
                size_t idx = (size_t)row * N + col;
                if (mode == 1) {
                    Cb[idx] = f2b(fmaxf(o, 0.f));
                } else {
                    float kf = keepf[row];
                    Cf[idx] = (Cf[idx] + o) * kf;
                }
            }
        }
    }
}

// ---------------- fused Q/K/V projection: grid (200, 4, 3), BK=64 sub-tiles ----
__global__ __launch_bounds__(256) void gemm_qkv(const ushort_t* __restrict__ Aq,
                                                const ushort_t* __restrict__ Akv,
                                                const ushort_t* __restrict__ Bqkv,
                                                const float* __restrict__ bq,
                                                const float* __restrict__ bk,
                                                const float* __restrict__ bv,
                                                ushort_t* __restrict__ qkv) {
    __shared__ ushort_t sA[2][128 * 32];
    __shared__ ushort_t sB[2][128 * 32];
    int z = blockIdx.z;
    const ushort_t* A = (z == 0) ? Aq : Akv;
    const ushort_t* Bt = Bqkv + (size_t)z * DD * DD;
    const float* bias = (z == 0) ? bq : (z == 1) ? bk : bv;
    ushort_t* C = qkv + (size_t)z * BL * DD;

    int t = threadIdx.x;
    int w = t >> 6, lane = t & 63;
    int wm = w & 1, wn = w >> 1;
    int m0 = blockIdx.x * 128, n0 = blockIdx.y * 128;
    int lr = lane & 15, lq = lane >> 4;

    f32x4 acc[4][4] = {};

    for (int k0 = 0; k0 < DD; k0 += 64) {
        #pragma unroll
        for (int hh = 0; hh < 2; hh++) {
            #pragma unroll
            for (int r = 0; r < 2; r++) {
                int e = (r * 256 + t) * 8;
                int row = e >> 5, col = e & 31;
                gload16(A + (size_t)(m0 + row) * DD + k0 + hh * 32 + col,
                        sA[hh] + (r * 256 + w * 64) * 8);
                gload16(Bt + (size_t)(n0 + row) * DD + k0 + hh * 32 + col,
                        sB[hh] + (r * 256 + w * 64) * 8);
            }
        }
        __syncthreads();

        #pragma unroll
        for (int hh = 0; hh < 2; hh++) {
            short8 af[4], bf[4];
            #pragma unroll
            for (int mt = 0; mt < 4; mt++)
                af[mt] = *(const short8*)(sA[hh] + (wm * 64 + mt * 16 + lr) * 32 + lq * 8);
            #pragma unroll
            for (int nt = 0; nt < 4; nt++)
                bf[nt] = *(const short8*)(sB[hh] + (wn * 64 + nt * 16 + lr) * 32 + lq * 8);
            #pragma unroll
            for (int mt = 0; mt < 4; mt++)
                #pragma unroll
                for (int nt = 0; nt < 4; nt++)
                    acc[mt][nt] = __builtin_amdgcn_mfma_f32_16x16x32_bf16(af[mt], bf[nt], acc[mt][nt], 0, 0, 0);
        }
        __syncthreads();
    }

    #pragma unroll
    for (int nt = 0; nt < 4; nt++) {
        int col = n0 + wn * 64 + nt * 16 + lr;
        float bv2 = bias[col];
        #pragma unroll
        for (int mt = 0; mt < 4; mt++) {
            int rowb = m0 + wm * 64 + mt * 16 + lq * 4;
            #pragma unroll
            for (int r = 0; r < 4; r++) {
                int row = rowb + r;
                C[(size_t)row * DD + col] = f2b(acc[mt][nt][r] + bv2);
            }
        }
    }
}

// ---------------- attention v5: K/Q frags direct from global, LDS = P + V^T ----
// K fragments are qtile-invariant -> loaded ONCE into registers (32 VGPRs) and
// held across all 4 qtiles. No K staging, no kms array. 61,440 B LDS, 2 blk/CU.
// All register arrays statically indexed (round-6 scratch-spill lesson).
#define ATTN_LDS_BYTES 61440
__global__ __launch_bounds__(256, 2) void attn5_kernel(const ushort_t* __restrict__ q,
                                                       const ushort_t* __restrict__ k,
                                                       const ushort_t* __restrict__ v,
                                                       const float* __restrict__ kmf,
                                                       float* __restrict__ xout) {
    extern __shared__ ushort_t su[];
    ushort_t* sP = su;                  // [64][232]
    ushort_t* sVt = su + 14848;         // [64][232]
    float* redm = (float*)(su + 29696); // [256]
    float* reds = redm + 256;           // [256]

    int t = threadIdx.x;
    int b = blockIdx.x >> 3, h = blockIdx.x & 7;
    int w = t >> 6, lane = t & 63;
    int lr = lane & 15, lq = lane >> 4;

    const ushort_t* kg = k + (size_t)b * LL * DD + h * DK;
    const ushort_t* vg = v + (size_t)b * LL * DD + h * DK;
    const ushort_t* qg = q + (size_t)b * LL * DD + h * DK;
    float* og = xout + (size_t)b * LL * DD + h * DK;

    // stage V^T once: word (d*116 + tt) holds keys {2tt, 2tt+1} for dim d
    for (int idx = t; idx < 1024; idx += 256) {
        int s = idx >> 7, tt = idx & 127;
        if (tt < 116) {
            uint_t outw[8];
            if (tt < 100) {
                int j0 = tt * 2;
                uint4 a = *(const uint4*)(vg + (size_t)j0 * DD + s * 8);
                uint4 c = *(const uint4*)(vg + (size_t)(j0 + 1) * DD + s * 8);
                uint_t av[4] = {a.x, a.y, a.z, a.w};
                uint_t cv[4] = {c.x, c.y, c.z, c.w};
                #pragma unroll
                for (int i = 0; i < 8; i++) {
                    uint_t lo = (av[i >> 1] >> ((i & 1) * 16)) & 0xFFFFu;
                    uint_t hi = (cv[i >> 1] >> ((i & 1) * 16)) & 0xFFFFu;
                    outw[i] = lo | (hi << 16);
                }
            } else {
                #pragma unroll
                for (int i = 0; i < 8; i++) outw[i] = 0;
            }
            #pragma unroll
            for (int i = 0; i < 8; i++)
                ((uint_t*)sVt)[(s * 8 + i) * 116 + tt] = outw[i];
        }
    }
    // (first sVt read happens after >=2 barriers in qtile 0 — no barrier here)

    // K fragments + key masks, hoisted across qtiles (B-frag = natural row chunks)
    short8 bfK[2][4];
    float km[4];
    #pragma unroll
    for (int nt = 0; nt < 4; nt++) {
        int j = w * 64 + nt * 16 + lr;
        int jc = (j < LL) ? j : (LL - 1);
        #pragma unroll
        for (int ks = 0; ks < 2; ks++)
            bfK[ks][nt] = *(const short8*)(kg + (size_t)jc * DD + ks * 32 + lq * 8);
        km[nt] = (j < LL) ? kmf[b * LL + j] : 0.f;
    }

    for (int qt = 0; qt < 4; qt++) {
        int q0 = qt * 64;
        // Q fragments direct from global (clamped rows never written back)
        short8 af[2][4];
        #pragma unroll
        for (int ks = 0; ks < 2; ks++)
            #pragma unroll
            for (int mt = 0; mt < 4; mt++) {
                int grow = q0 + mt * 16 + lr;
                if (grow > LL - 1) grow = LL - 1;
                af[ks][mt] = *(const short8*)(qg + (size_t)grow * DD + ks * 32 + lq * 8);
            }

        // S = Q @ K^T ; wave w covers keys w*64..w*64+63
        f32x4 accS[4][4] = {};
        #pragma unroll
        for (int ks = 0; ks < 2; ks++)
            #pragma unroll
            for (int nt = 0; nt < 4; nt++)
                #pragma unroll
                for (int mt = 0; mt < 4; mt++)
                    accS[mt][nt] = __builtin_amdgcn_mfma_f32_16x16x32_bf16(af[ks][mt], bfK[ks][nt], accS[mt][nt], 0, 0, 0);

        // mask + scale + per-wave row max (mask REPLACES garbage from clamped rows)
        float rmax[4][4];
        #pragma unroll
        for (int mt = 0; mt < 4; mt++) {
            #pragma unroll
            for (int r = 0; r < 4; r++) {
                int qrow = q0 + mt * 16 + lq * 4 + r;
                float m = -1e9f;
                #pragma unroll
                for (int nt = 0; nt < 4; nt++) {
                    int j = w * 64 + nt * 16 + lr;
                    bool ok = (j <= qrow) && (km[nt] != 0.f);
                    float s = ok ? accS[mt][nt][r] * 0.125f : -1e9f;
                    accS[mt][nt][r] = s;
                    m = fmaxf(m, s);
                }
                #pragma unroll
                for (int off = 1; off < 16; off <<= 1)
                    m = fmaxf(m, __shfl_xor(m, off));
                rmax[mt][r] = m;
            }
        }
        if (lr == 0) {
            #pragma unroll
            for (int mt = 0; mt < 4; mt++)
                #pragma unroll
                for (int r = 0; r < 4; r++)
                    redm[w * 64 + mt * 16 + lq * 4 + r] = rmax[mt][r];
        }
        __syncthreads();

        // exp + per-wave row sum
        float gmx[4][4], rsum[4][4];
        #pragma unroll
        for (int mt = 0; mt < 4; mt++) {
            #pragma unroll
            for (int r = 0; r < 4; r++) {
                int row = mt * 16 + lq * 4 + r;
                float gm = fmaxf(fmaxf(redm[row], redm[64 + row]),
                                 fmaxf(redm[128 + row], redm[192 + row]));
                gmx[mt][r] = gm;
                float ps = 0.f;
                #pragma unroll
                for (int nt = 0; nt < 4; nt++) {
                    float e = __expf(accS[mt][nt][r] - gm);
                    accS[mt][nt][r] = e;
                    ps += e;
                }
                #pragma unroll
                for (int off = 1; off < 16; off <<= 1)
                    ps += __shfl_xor(ps, off);
                rsum[mt][r] = ps;
            }
        }
        if (lr == 0) {
            #pragma unroll
            for (int mt = 0; mt < 4; mt++)
                #pragma unroll
                for (int r = 0; r < 4; r++)
                    reds[w * 64 + mt * 16 + lq * 4 + r] = rsum[mt][r];
        }
        __syncthreads();

        // normalize -> bf16 P. all-masked row -> inv=0 -> exact zeros
        #pragma unroll
        for (int mt = 0; mt < 4; mt++) {
            #pragma unroll
            for (int r = 0; r < 4; r++) {
                int row = mt * 16 + lq * 4 + r;
                float tot = reds[row] + reds[64 + row] + reds[128 + row] + reds[192 + row];
                float inv = (gmx[mt][r] < -5e8f) ? 0.f : 1.f / tot;
                #pragma unroll
                for (int nt = 0; nt < 4; nt++) {
                    int col = w * 64 + nt * 16 + lr;
                    if (col < 224)
                        sP[row * 232 + col] = f2b(accS[mt][nt][r] * inv);
                }
            }
        }
        __syncthreads();

        // O = P @ V ; wave w covers d-tile w*16..w*16+15 ; keys 0..223
        f32x4 accO[4] = {};
        #pragma unroll
        for (int ks2 = 0; ks2 < 7; ks2++) {
            short8 bfv = *(const short8*)(sVt + (w * 16 + lr) * 232 + ks2 * 32 + lq * 8);
            #pragma unroll
            for (int mt = 0; mt < 4; mt++) {
                short8 afp = *(const short8*)(sP + (mt * 16 + lr) * 232 + ks2 * 32 + lq * 8);
                accO[mt] = __builtin_amdgcn_mfma_f32_16x16x32_bf16(afp, bfv, accO[mt], 0, 0, 0);
            }
        }
        #pragma unroll
        for (int mt = 0; mt < 4; mt++) {
            #pragma unroll
            for (int r = 0; r < 4; r++) {
                int row = q0 + mt * 16 + lq * 4 + r;
                if (row < LL)
                    og[(size_t)row * DD + w * 16 + lr] = accO[mt][r];
            }
        }
        __syncthreads();   // sP reads done before next qtile overwrites it
    }
}

extern "C" void kernel_launch(void* const* d_in, const int* in_sizes, int n_in,
                              void* d_out, int out_size, void* d_ws, size_t ws_size,
                              hipStream_t stream) {
    const int* log_seqs = (const int*)d_in[0];
    const float* seqs_embs = (const float*)d_in[1];
    const int* entire = (const int*)d_in[2];
    const float* Wq = (const float*)d_in[3];
    const float* bq = (const float*)d_in[4];
    const float* Wk = (const float*)d_in[5];
    const float* bk = (const float*)d_in[6];
    const float* Wv = (const float*)d_in[7];
    const float* bv = (const float*)d_in[8];
    const float* lag = (const float*)d_in[9];
    const float* lab = (const float*)d_in[10];
    const float* lfg = (const float*)d_in[11];
    const float* lfb = (const float*)d_in[12];
    const float* W1 = (const float*)d_in[13];
    const float* b1 = (const float*)d_in[14];
    const float* W2 = (const float*)d_in[15];
    const float* b2 = (const float*)d_in[16];
    const float* llg = (const float*)d_in[17];
    const float* llb = (const float*)d_in[18];
    float* out = (float*)d_out;
    float* ws = (float*)d_ws;

    hipFuncSetAttribute((const void*)attn5_kernel,
                        hipFuncAttributeMaxDynamicSharedMemorySize,
                        ATTN_LDS_BYTES);

    // workspace ~241 MB (262.45 MB proven safe)
    const size_t n = (size_t)BL * DD;
    float* tgt = ws;
    float* aout = ws + n;
    ushort_t* srcb = (ushort_t*)(ws + 2 * n);
    ushort_t* qb = srcb + n;
    ushort_t* kb = qb + n;
    ushort_t* vb = kb + n;
    ushort_t* lnb = vb + n;          // dedicated: read by gemm_qkv z=0 while z=2 writes vb
    ushort_t* WqkvT = lnb + n;
    ushort_t* W1T = WqkvT + (size_t)NBLK * 3 * DD * DD;
    ushort_t* W2T = W1T + (size_t)NBLK * DD * DD;
    float* keepf = (float*)(W2T + (size_t)NBLK * DD * DD);
    float* kmf = keepf + BL;
    ushort_t* hb = qb;               // FFN1 out: qb dead after attention

    mask_kernel<<<(BL + 255) / 256, 256, 0, stream>>>(log_seqs, entire, keepf, kmf);
    prep_kernel<<<BL, 256, 0, stream>>>(log_seqs, seqs_embs, tgt, srcb);
    dim3 tw(16, 16, 10);
    wtrans10_kernel<<<tw, 256, 0, stream>>>(Wq, Wk, Wv, W1, W2, WqkvT, W1T, W2T);

    dim3 gg(BL / 128, DD / 128);
    dim3 gq(BL / 128, DD / 128, 3);
    for (int i = 0; i < NBLK; i++) {
        size_t wo = (size_t)i * DD * DD;
        // lnb = bf16(LN(tgt, ln_attn))
        ln_kernel<<<BL, 256, 0, stream>>>(tgt, nullptr, nullptr, lnb,
                                          lag + i * DD, lab + i * DD, nullptr);
        // fused q,k,v projections -> qb,kb,vb (bf16)
        gemm_qkv<<<gq, 256, 0, stream>>>(lnb, srcb, WqkvT + (size_t)i * 3 * DD * DD,
                                         bq + i * DD, bk + i * DD, bv + i * DD, qb);
        // attention (MFMA) -> aout fp32
        attn5_kernel<<<BB * HH, 256, ATTN_LDS_BYTES, stream>>>(qb, kb, vb, kmf, aout);
        // tgt = LN(aout (+tgt)), bf16 copy to lnb
        ln_kernel<<<BL, 256, 0, stream>>>(aout, (i == 0) ? nullptr : tgt, tgt, lnb,
                                          lfg + i * DD, lfb + i * DD, nullptr);
        // hb = bf16(relu(lnb @ W1 + b1))
        gemm_mfma<<<gg, 256, 0, stream>>>(lnb, W1T + wo, b1 + i * DD, nullptr, hb,
                                          nullptr, 1, BL, DD, DD);
        // tgt = (tgt + hb @ W2 + b2) * keep
        gemm_mfma<<<gg, 256, 0, stream>>>(hb, W2T + wo, b2 + i * DD, tgt, nullptr,
                                          keepf, 2, BL, DD, DD);
    }
    ln_kernel<<<BL, 256, 0, stream>>>(tgt, nullptr, out, nullptr, llg, llb, keepf);
}